// Round 1
// baseline (907.948 us; speedup 1.0000x reference)
//
#include <hip/hip_runtime.h>
#include <cstdint>
#include <cstddef>

// Problem constants (static shapes from the reference)
#define CDIM  1024      // C
#define DTDIM 1024      // D*T
#define MDIM  65536     // B * D * T
#define BDIM  64        // B (batch / sentences)
#define VNUM  50        // valid_num

typedef __attribute__((ext_vector_type(8))) short bf16x8;
typedef __attribute__((ext_vector_type(4))) float f32x4;

__device__ __forceinline__ float bf2f(unsigned int u16) {
  return __uint_as_float(u16 << 16);
}
__device__ __forceinline__ unsigned short f2bf(float x) {
  unsigned int u = __float_as_uint(x);
  u += 0x7fffu + ((u >> 16) & 1u);   // round-to-nearest-even
  return (unsigned short)(u >> 16);
}

// async global -> LDS, 16B per lane; LDS dest is wave-uniform base + lane*16
__device__ __forceinline__ void gload16(const void* g, void* l) {
  __builtin_amdgcn_global_load_lds((const __attribute__((address_space(1))) void*)g,
                                   (__attribute__((address_space(3))) void*)l,
                                   16, 0, 0);
}

// ---------------------------------------------------------------------------
// 1) videos fp32 [b][c][dt]  ->  At bf16 [b*1024+dt][c]   (LDS-tiled transpose)
// grid (32 dt-tiles, 32 c-tiles, 64 b), 256 thr
__global__ void k_transpose_videos(const float* __restrict__ vid,
                                   unsigned short* __restrict__ At) {
  __shared__ float t[32][33];
  const int tx = threadIdx.x & 31, ty = threadIdx.x >> 5;
  const int dt0 = blockIdx.x * 32, c0 = blockIdx.y * 32, b = blockIdx.z;
  const float* src = vid + ((size_t)b * CDIM + c0) * DTDIM + dt0;
#pragma unroll
  for (int i = 0; i < 4; i++) {
    const int cl = ty + i * 8;
    t[cl][tx] = src[(size_t)cl * DTDIM + tx];
  }
  __syncthreads();
  unsigned short* dst = At + ((size_t)b * DTDIM + dt0) * CDIM + c0;
#pragma unroll
  for (int i = 0; i < 4; i++) {
    const int dl = ty + i * 8;
    dst[(size_t)dl * CDIM + tx] = f2bf(t[tx][dl]);
  }
}

// ---------------------------------------------------------------------------
// 2) W_v fp32 [kb][c][f] -> Wt bf16 [kb*256+f][c]
// grid (8 f-tiles, 32 c-tiles, 4 kb), 256 thr
__global__ void k_transpose_W(const float* __restrict__ W,
                              unsigned short* __restrict__ Wt) {
  __shared__ float t[32][33];
  const int tx = threadIdx.x & 31, ty = threadIdx.x >> 5;
  const int f0 = blockIdx.x * 32, c0 = blockIdx.y * 32, kb = blockIdx.z;
  const float* src = W + ((size_t)kb * CDIM + c0) * 256 + f0;
#pragma unroll
  for (int i = 0; i < 4; i++) {
    const int cl = ty + i * 8;
    t[cl][tx] = src[(size_t)cl * 256 + tx];
  }
  __syncthreads();
  unsigned short* dst = Wt + ((size_t)(kb * 256 + f0)) * CDIM + c0;
#pragma unroll
  for (int i = 0; i < 4; i++) {
    const int fl = ty + i * 8;
    dst[(size_t)fl * CDIM + tx] = f2bf(t[tx][fl]);
  }
}

// ---------------------------------------------------------------------------
// 3) per-row fp32 sums of a bf16 [nrows][1024] matrix (one wave per row)
__global__ void k_row_sums(const unsigned short* __restrict__ A,
                           float* __restrict__ out, int nrows) {
  const int wave = threadIdx.x >> 6, lane = threadIdx.x & 63;
  const int row = blockIdx.x * 4 + wave;
  if (row >= nrows) return;
  const unsigned short* r = A + (size_t)row * 1024;
  float s = 0.f;
#pragma unroll
  for (int h = 0; h < 2; h++) {
    const uint4 u = *reinterpret_cast<const uint4*>(r + h * 512 + lane * 8);
    s += bf2f(u.x & 0xffffu) + bf2f(u.x >> 16);
    s += bf2f(u.y & 0xffffu) + bf2f(u.y >> 16);
    s += bf2f(u.z & 0xffffu) + bf2f(u.z >> 16);
    s += bf2f(u.w & 0xffffu) + bf2f(u.w >> 16);
  }
#pragma unroll
  for (int o = 32; o; o >>= 1) s += __shfl_down(s, o);
  if (lane == 0) out[row] = s;
}

// ---------------------------------------------------------------------------
// 4) sentence projection (fp32): s_cat[s][n] = sum_c (sent[s][c]-mu_s)*W_s[kb][c][f] + b_s
//    writes bf16 scat row (K-contig for GEMM2) and atomically accumulates snorm2[s]
// grid (64 s, 4 j), 256 thr; thread computes n = j*256 + tid
__global__ void k_scat(const float* __restrict__ sent, const float* __restrict__ Ws,
                       const float* __restrict__ bs, unsigned short* __restrict__ scat,
                       float* __restrict__ snorm2) {
  const int s = blockIdx.x, j = blockIdx.y, tid = threadIdx.x;
  __shared__ float sc[1024];
  __shared__ float red[4];
  float p = 0.f;
#pragma unroll
  for (int q = 0; q < 4; q++) {
    const float x = sent[(size_t)s * 1024 + tid + q * 256];
    sc[tid + q * 256] = x;
    p += x;
  }
#pragma unroll
  for (int o = 32; o; o >>= 1) p += __shfl_down(p, o);
  const int wave = tid >> 6, lane = tid & 63;
  if (lane == 0) red[wave] = p;
  __syncthreads();
  const float mean = (red[0] + red[1] + red[2] + red[3]) * (1.f / 1024.f);
  float acc = 0.f;
  const float* W = Ws + ((size_t)j * 1024) * 256 + tid;
  for (int c = 0; c < 1024; c++) acc += (sc[c] - mean) * W[(size_t)c * 256];
  const int n = j * 256 + tid;
  const float val = acc + bs[n];
  scat[(size_t)s * 1024 + n] = f2bf(val);
  float v2 = val * val;
#pragma unroll
  for (int o = 32; o; o >>= 1) v2 += __shfl_down(v2, o);
  if (lane == 0) atomicAdd(&snorm2[s], v2);
}

// ---------------------------------------------------------------------------
// 5) GEMM1: vcat[m][n] = sum_k At[m][k]*Wt[n][k]  - mu[m]*csW[n] + bv[n]
//    M=65536, N=1024, K=1024, BM=BN=128, BK=32, 256 thr (4 waves in 2x2)
//    fused: bf16 vcat write + atomic rowwise sum-of-squares into vnorm2[m]
__global__ void k_gemm1(const unsigned short* __restrict__ At,
                        const unsigned short* __restrict__ Wt,
                        const float* __restrict__ vsums, const float* __restrict__ csW,
                        const float* __restrict__ bv,
                        unsigned short* __restrict__ vcat, float* __restrict__ vnorm2) {
  __shared__ alignas(16) unsigned short sA[128 * 32];
  __shared__ alignas(16) unsigned short sB[128 * 32];
  const int tid = threadIdx.x;
  const int wave = tid >> 6, lane = tid & 63;
  const int quad = lane >> 4, l16 = lane & 15;
  const int m0 = blockIdx.x * 128, n0 = blockIdx.y * 128;
  const int wm = (wave & 1) * 64, wn = (wave >> 1) * 64;

  f32x4 acc[4][4];
#pragma unroll
  for (int i = 0; i < 4; i++)
#pragma unroll
    for (int j = 0; j < 4; j++) acc[i][j] = f32x4{0.f, 0.f, 0.f, 0.f};

  const int rowA0 = (wave * 2 + 0) * 16 + (lane >> 2);
  const int rowA1 = (wave * 2 + 1) * 16 + (lane >> 2);
  const int kk = (lane & 3) * 8;
  const unsigned short* gA0 = At + (size_t)(m0 + rowA0) * CDIM + kk;
  const unsigned short* gA1 = At + (size_t)(m0 + rowA1) * CDIM + kk;
  const unsigned short* gB0 = Wt + (size_t)(n0 + rowA0) * CDIM + kk;
  const unsigned short* gB1 = Wt + (size_t)(n0 + rowA1) * CDIM + kk;
  unsigned short* lA0 = &sA[(wave * 2 + 0) * 512];
  unsigned short* lA1 = &sA[(wave * 2 + 1) * 512];
  unsigned short* lB0 = &sB[(wave * 2 + 0) * 512];
  unsigned short* lB1 = &sB[(wave * 2 + 1) * 512];

  for (int kt = 0; kt < 32; ++kt) {
    const int koff = kt * 32;
    gload16(gA0 + koff, lA0);
    gload16(gA1 + koff, lA1);
    gload16(gB0 + koff, lB0);
    gload16(gB1 + koff, lB1);
    __syncthreads();
    bf16x8 aF[4], bF[4];
#pragma unroll
    for (int i = 0; i < 4; i++)
      aF[i] = *reinterpret_cast<const bf16x8*>(&sA[(wm + i * 16 + l16) * 32 + quad * 8]);
#pragma unroll
    for (int j = 0; j < 4; j++)
      bF[j] = *reinterpret_cast<const bf16x8*>(&sB[(wn + j * 16 + l16) * 32 + quad * 8]);
#pragma unroll
    for (int i = 0; i < 4; i++)
#pragma unroll
      for (int j = 0; j < 4; j++)
        acc[i][j] = __builtin_amdgcn_mfma_f32_16x16x32_bf16(aF[i], bF[j], acc[i][j], 0, 0, 0);
    __syncthreads();
  }

  // epilogue: centering correction, bf16 store, fused row sum-of-squares
  const float inv1024 = 1.f / 1024.f;
#pragma unroll
  for (int i = 0; i < 4; i++) {
    const int rbase = m0 + wm + i * 16 + quad * 4;   // 4 consecutive rows
    const float4 vs = *reinterpret_cast<const float4*>(&vsums[rbase]);
    const float mu[4] = {vs.x * inv1024, vs.y * inv1024, vs.z * inv1024, vs.w * inv1024};
    float ss[4] = {0.f, 0.f, 0.f, 0.f};
#pragma unroll
    for (int j = 0; j < 4; j++) {
      const int col = n0 + wn + j * 16 + l16;
      const float cs = csW[col];
      const float bb = bv[col];
#pragma unroll
      for (int r = 0; r < 4; r++) {
        const float val = acc[i][j][r] - mu[r] * cs + bb;
        vcat[(size_t)(rbase + r) * CDIM + col] = f2bf(val);
        ss[r] += val * val;
      }
    }
#pragma unroll
    for (int r = 0; r < 4; r++) {
      float v = ss[r];
      v += __shfl_xor(v, 1); v += __shfl_xor(v, 2);
      v += __shfl_xor(v, 4); v += __shfl_xor(v, 8);
      if (l16 == 0) atomicAdd(&vnorm2[rbase + r], v);
    }
  }
}

// ---------------------------------------------------------------------------
// 6) GEMM2: sim[s][m] = (scat[s]·vcat[m]) / (max(|vcat_m|,eps)*max(|scat_s|,eps))
//    tile 64(s) x 128(m), K=1024; fused mask + positive_map write
__global__ void k_gemm2(const unsigned short* __restrict__ scat,
                        const unsigned short* __restrict__ vcat,
                        const float* __restrict__ snorm2, const float* __restrict__ vnorm2,
                        const int* __restrict__ mask,
                        float* __restrict__ sim, float* __restrict__ pm) {
  __shared__ alignas(16) unsigned short sS[64 * 32];
  __shared__ alignas(16) unsigned short sV[128 * 32];
  const int tid = threadIdx.x;
  const int wave = tid >> 6, lane = tid & 63;
  const int quad = lane >> 4, l16 = lane & 15;
  const int m0 = blockIdx.x * 128;

  f32x4 acc[4][2];
#pragma unroll
  for (int i = 0; i < 4; i++)
#pragma unroll
    for (int j = 0; j < 2; j++) acc[i][j] = f32x4{0.f, 0.f, 0.f, 0.f};

  const int rS = wave * 16 + (lane >> 2);
  const int rV0 = (wave * 2 + 0) * 16 + (lane >> 2);
  const int rV1 = (wave * 2 + 1) * 16 + (lane >> 2);
  const int kk = (lane & 3) * 8;
  const unsigned short* gS = scat + (size_t)rS * CDIM + kk;
  const unsigned short* gV0 = vcat + (size_t)(m0 + rV0) * CDIM + kk;
  const unsigned short* gV1 = vcat + (size_t)(m0 + rV1) * CDIM + kk;
  unsigned short* lS = &sS[wave * 512];
  unsigned short* lV0 = &sV[(wave * 2 + 0) * 512];
  unsigned short* lV1 = &sV[(wave * 2 + 1) * 512];

  for (int kt = 0; kt < 32; ++kt) {
    const int koff = kt * 32;
    gload16(gS + koff, lS);
    gload16(gV0 + koff, lV0);
    gload16(gV1 + koff, lV1);
    __syncthreads();
    bf16x8 aF[4], bF[2];
#pragma unroll
    for (int i = 0; i < 4; i++)
      aF[i] = *reinterpret_cast<const bf16x8*>(&sS[(i * 16 + l16) * 32 + quad * 8]);
#pragma unroll
    for (int j = 0; j < 2; j++)
      bF[j] = *reinterpret_cast<const bf16x8*>(&sV[(wave * 32 + j * 16 + l16) * 32 + quad * 8]);
#pragma unroll
    for (int i = 0; i < 4; i++)
#pragma unroll
      for (int j = 0; j < 2; j++)
        acc[i][j] = __builtin_amdgcn_mfma_f32_16x16x32_bf16(aF[i], bF[j], acc[i][j], 0, 0, 0);
    __syncthreads();
  }

  const int b0 = m0 >> 10;   // batch index of this m-chunk (uniform per block)
#pragma unroll
  for (int j = 0; j < 2; j++) {
    const int m = m0 + wave * 32 + j * 16 + l16;
    const float vn = fmaxf(sqrtf(vnorm2[m]), 1e-8f);
    const int mk = mask[m];
#pragma unroll
    for (int i = 0; i < 4; i++) {
#pragma unroll
      for (int r = 0; r < 4; r++) {
        const int s = i * 16 + quad * 4 + r;
        const float sn = fmaxf(sqrtf(snorm2[s]), 1e-8f);
        float val = acc[i][j][r] / (vn * sn);
        if (mk == 0) val = -__builtin_inff();
        sim[(size_t)s * MDIM + m] = val;
        if (s == b0) pm[m] = val;
      }
    }
  }
}

// ---------------------------------------------------------------------------
// 7) per-(s,b): top-50 of sim row, IoU penalty, score
// grid (64 b, 64 s), 256 thr
__global__ void k_topk(const float* __restrict__ sim, const float* __restrict__ iou,
                       const float* __restrict__ lam, float* __restrict__ scores) {
  const int b = blockIdx.x, s = blockIdx.y, tid = threadIdx.x;
  __shared__ float v[1024];
  __shared__ float rv[4];
  __shared__ int ri[4];
  __shared__ float tv[VNUM];
  __shared__ int tix[VNUM];
  __shared__ float pen[VNUM];
  const float* row = sim + (size_t)s * MDIM + (size_t)b * 1024;
#pragma unroll
  for (int q = 0; q < 4; q++) v[tid + q * 256] = row[tid + q * 256];
  __syncthreads();
  const int wave = tid >> 6, lane = tid & 63;
  for (int k = 0; k < VNUM; k++) {
    float bv = -__builtin_inff();
    int bi = 1 << 30;
#pragma unroll
    for (int q = 0; q < 4; q++) {
      const int idx = tid + q * 256;
      const float x = v[idx];
      if (x > bv || (x == bv && idx < bi)) { bv = x; bi = idx; }
    }
#pragma unroll
    for (int o = 32; o; o >>= 1) {
      const float ov = __shfl_down(bv, o);
      const int oi = __shfl_down(bi, o);
      if (ov > bv || (ov == bv && oi < bi)) { bv = ov; bi = oi; }
    }
    if (lane == 0) { rv[wave] = bv; ri[wave] = bi; }
    __syncthreads();
    if (tid == 0) {
      float wv = rv[0]; int wi = ri[0];
      for (int w = 1; w < 4; w++)
        if (rv[w] > wv || (rv[w] == wv && ri[w] < wi)) { wv = rv[w]; wi = ri[w]; }
      tv[k] = wv; tix[k] = wi;
      v[wi] = -__builtin_inff();
    }
    __syncthreads();
  }
  if (tid < VNUM) pen[tid] = 0.f;
  __syncthreads();
  for (int p = tid; p < VNUM * VNUM; p += 256) {
    const int l = p / VNUM, kkk = p % VNUM;
    if (l > kkk) {
      const float u = iou[(size_t)tix[l] * 1024 + tix[kkk]];
      atomicAdd(&pen[kkk], u * u);
    }
  }
  __syncthreads();
  if (tid == 0) {
    const float lm = lam[0];
    float ssum = 0.f;
    for (int k = 0; k < VNUM; k++) ssum += tv[k] * expf(-pen[k] / lm);
    scores[s * 64 + b] = ssum * (1.f / VNUM);
  }
}

// ---------------------------------------------------------------------------
// 8) final 64x64 loss reduction
__global__ void k_loss(const float* __restrict__ scores, float* __restrict__ out) {
  __shared__ float S[64 * 64];
  __shared__ float diag[64];
  __shared__ float rmax[64], cmax[64];
  const int tid = threadIdx.x;
#pragma unroll
  for (int q = 0; q < 16; q++) S[tid + q * 256] = scores[tid + q * 256];
  __syncthreads();
  if (tid < 64) diag[tid] = S[tid * 64 + tid];
  __syncthreads();
  if (tid < 64) {
    float rm = 0.f, cm = 0.f;
    for (int x = 0; x < 64; x++) {
      if (x != tid) {
        const float cs = 0.2f + S[tid * 64 + x] - diag[tid];  // cost_s row tid
        rm = fmaxf(rm, fmaxf(cs, 0.f));
        const float ci = 0.2f + S[x * 64 + tid] - diag[tid];  // cost_im col tid
        cm = fmaxf(cm, fmaxf(ci, 0.f));
      }
    }
    rmax[tid] = rm; cmax[tid] = cm;
  }
  __syncthreads();
  if (tid == 0) {
    float L = 0.f;
    for (int t = 0; t < 64; t++) L += rmax[t] + cmax[t];
    out[0] = L * (1.f / 64.f);
  }
}

// ---------------------------------------------------------------------------
extern "C" void kernel_launch(void* const* d_in, const int* in_sizes, int n_in,
                              void* d_out, int out_size, void* d_ws, size_t ws_size,
                              hipStream_t stream) {
  (void)in_sizes; (void)n_in; (void)out_size; (void)ws_size;
  const float* videos = (const float*)d_in[0];
  const float* sent   = (const float*)d_in[1];
  const float* lam    = (const float*)d_in[2];
  const int*   mask   = (const int*)d_in[3];
  const float* iou    = (const float*)d_in[4];
  const float* W_v    = (const float*)d_in[6];
  const float* b_v    = (const float*)d_in[7];
  const float* W_s    = (const float*)d_in[8];
  const float* b_s    = (const float*)d_in[9];
  float* out = (float*)d_out;

  char* ws = (char*)d_ws;
  unsigned short* At   = (unsigned short*)(ws + 0);           // 128 MB
  unsigned short* vcat = (unsigned short*)(ws + 134217728);   // 128 MB
  float* sim           = (float*)(ws + 268435456);            // 16 MB
  unsigned short* Wt   = (unsigned short*)(ws + 285212672);   // 2 MB
  unsigned short* scat = (unsigned short*)(ws + 287309824);   // 128 KB
  float* vsums         = (float*)(ws + 287440896);            // 256 KB
  float* vnorm2        = (float*)(ws + 287703040);            // 256 KB
  float* snorm2        = (float*)(ws + 287965184);            // 256 B
  float* csW           = (float*)(ws + 287965440);            // 4 KB
  float* scores        = (float*)(ws + 287969536);            // 16 KB

  hipMemsetAsync(vnorm2, 0, 262144 + 256, stream);  // vnorm2 + snorm2 (adjacent)

  k_transpose_videos<<<dim3(32, 32, 64), 256, 0, stream>>>(videos, At);
  k_transpose_W<<<dim3(8, 32, 4), 256, 0, stream>>>(W_v, Wt);
  k_row_sums<<<16384, 256, 0, stream>>>(At, vsums, MDIM);
  k_row_sums<<<256, 256, 0, stream>>>(Wt, csW, 1024);
  k_scat<<<dim3(64, 4), 256, 0, stream>>>(sent, W_s, b_s, scat, snorm2);
  k_gemm1<<<dim3(512, 8), 256, 0, stream>>>(At, Wt, vsums, csW, b_v, vcat, vnorm2);
  k_gemm2<<<dim3(512), 256, 0, stream>>>(scat, vcat, snorm2, vnorm2, mask, sim, out + 1);
  k_topk<<<dim3(64, 64), 256, 0, stream>>>(sim, iou, lam, scores);
  k_loss<<<1, 256, 0, stream>>>(scores, out);
}

// Round 2
// 816.729 us; speedup vs baseline: 1.1117x; 1.1117x over previous
//
#include <hip/hip_runtime.h>
#include <cstdint>
#include <cstddef>

// Problem constants (static shapes from the reference)
#define CDIM  1024      // C
#define DTDIM 1024      // D*T
#define MDIM  65536     // B * D * T
#define BDIM  64        // B (batch / sentences)
#define VNUM  50        // valid_num

typedef __attribute__((ext_vector_type(8))) short bf16x8;
typedef __attribute__((ext_vector_type(4))) float f32x4;

__device__ __forceinline__ float bf2f(unsigned int u16) {
  return __uint_as_float(u16 << 16);
}
__device__ __forceinline__ unsigned short f2bf(float x) {
  unsigned int u = __float_as_uint(x);
  u += 0x7fffu + ((u >> 16) & 1u);   // round-to-nearest-even
  return (unsigned short)(u >> 16);
}

// async global -> LDS, 16B per lane; LDS dest is wave-uniform base + lane*16
__device__ __forceinline__ void gload16(const void* g, void* l) {
  __builtin_amdgcn_global_load_lds((const __attribute__((address_space(1))) void*)g,
                                   (__attribute__((address_space(3))) void*)l,
                                   16, 0, 0);
}

// ---------------------------------------------------------------------------
// 1) videos fp32 [b][c][dt]  ->  At bf16 [b*1024+dt][c]   (LDS-tiled transpose)
//    fused: per-(b,dt) row sums (for centering) via cross-lane reduce + atomic
// grid (32 dt-tiles, 32 c-tiles, 64 b), 256 thr
__global__ void k_transpose_videos(const float* __restrict__ vid,
                                   unsigned short* __restrict__ At,
                                   float* __restrict__ vsums) {
  __shared__ float t[32][33];
  const int tx = threadIdx.x & 31, ty = threadIdx.x >> 5;
  const int dt0 = blockIdx.x * 32, c0 = blockIdx.y * 32, b = blockIdx.z;
  const float* src = vid + ((size_t)b * CDIM + c0) * DTDIM + dt0;
#pragma unroll
  for (int i = 0; i < 4; i++) {
    const int cl = ty + i * 8;
    t[cl][tx] = src[(size_t)cl * DTDIM + tx];
  }
  __syncthreads();
  unsigned short* dst = At + ((size_t)b * DTDIM + dt0) * CDIM + c0;
#pragma unroll
  for (int i = 0; i < 4; i++) {
    const int dl = ty + i * 8;
    const float val = t[tx][dl];
    dst[(size_t)dl * CDIM + tx] = f2bf(val);
    // partial row sum over the 32 c values of this tile (lanes share ty)
    float s = val;
    s += __shfl_xor(s, 1);  s += __shfl_xor(s, 2);
    s += __shfl_xor(s, 4);  s += __shfl_xor(s, 8);
    s += __shfl_xor(s, 16);
    if (tx == 0) atomicAdd(&vsums[(size_t)b * DTDIM + dt0 + dl], s);
  }
}

// ---------------------------------------------------------------------------
// 2) W_v fp32 [kb][c][f] -> Wt bf16 [kb*256+f][c]
// grid (8 f-tiles, 32 c-tiles, 4 kb), 256 thr
__global__ void k_transpose_W(const float* __restrict__ W,
                              unsigned short* __restrict__ Wt) {
  __shared__ float t[32][33];
  const int tx = threadIdx.x & 31, ty = threadIdx.x >> 5;
  const int f0 = blockIdx.x * 32, c0 = blockIdx.y * 32, kb = blockIdx.z;
  const float* src = W + ((size_t)kb * CDIM + c0) * 256 + f0;
#pragma unroll
  for (int i = 0; i < 4; i++) {
    const int cl = ty + i * 8;
    t[cl][tx] = src[(size_t)cl * 256 + tx];
  }
  __syncthreads();
  unsigned short* dst = Wt + ((size_t)(kb * 256 + f0)) * CDIM + c0;
#pragma unroll
  for (int i = 0; i < 4; i++) {
    const int fl = ty + i * 8;
    dst[(size_t)fl * CDIM + tx] = f2bf(t[tx][fl]);
  }
}

// ---------------------------------------------------------------------------
// 3) per-row fp32 sums of a bf16 [nrows][1024] matrix (one wave per row)
__global__ void k_row_sums(const unsigned short* __restrict__ A,
                           float* __restrict__ out, int nrows) {
  const int wave = threadIdx.x >> 6, lane = threadIdx.x & 63;
  const int row = blockIdx.x * 4 + wave;
  if (row >= nrows) return;
  const unsigned short* r = A + (size_t)row * 1024;
  float s = 0.f;
#pragma unroll
  for (int h = 0; h < 2; h++) {
    const uint4 u = *reinterpret_cast<const uint4*>(r + h * 512 + lane * 8);
    s += bf2f(u.x & 0xffffu) + bf2f(u.x >> 16);
    s += bf2f(u.y & 0xffffu) + bf2f(u.y >> 16);
    s += bf2f(u.z & 0xffffu) + bf2f(u.z >> 16);
    s += bf2f(u.w & 0xffffu) + bf2f(u.w >> 16);
  }
#pragma unroll
  for (int o = 32; o; o >>= 1) s += __shfl_down(s, o);
  if (lane == 0) out[row] = s;
}

// ---------------------------------------------------------------------------
// 4) sentence projection (fp32): s_cat[s][n] = sum_c (sent[s][c]-mu_s)*W_s[kb][c][f] + b_s
//    writes bf16 scat row (K-contig for GEMM2) and atomically accumulates snorm2[s]
// grid (64 s, 4 j), 256 thr; thread computes n = j*256 + tid
__global__ void k_scat(const float* __restrict__ sent, const float* __restrict__ Ws,
                       const float* __restrict__ bs, unsigned short* __restrict__ scat,
                       float* __restrict__ snorm2) {
  const int s = blockIdx.x, j = blockIdx.y, tid = threadIdx.x;
  __shared__ float sc[1024];
  __shared__ float red[4];
  float p = 0.f;
#pragma unroll
  for (int q = 0; q < 4; q++) {
    const float x = sent[(size_t)s * 1024 + tid + q * 256];
    sc[tid + q * 256] = x;
    p += x;
  }
#pragma unroll
  for (int o = 32; o; o >>= 1) p += __shfl_down(p, o);
  const int wave = tid >> 6, lane = tid & 63;
  if (lane == 0) red[wave] = p;
  __syncthreads();
  const float mean = (red[0] + red[1] + red[2] + red[3]) * (1.f / 1024.f);
  float acc = 0.f;
  const float* W = Ws + ((size_t)j * 1024) * 256 + tid;
  for (int c = 0; c < 1024; c++) acc += (sc[c] - mean) * W[(size_t)c * 256];
  const int n = j * 256 + tid;
  const float val = acc + bs[n];
  scat[(size_t)s * 1024 + n] = f2bf(val);
  float v2 = val * val;
#pragma unroll
  for (int o = 32; o; o >>= 1) v2 += __shfl_down(v2, o);
  if (lane == 0) atomicAdd(&snorm2[s], v2);
}

// ---------------------------------------------------------------------------
// 5) GEMM1: vcat[m][n] = sum_k At[m][k]*Wt[n][k]  - mu[m]*csW[n] + bv[n]
//    M=65536, N=1024, K=1024, BM=BN=128, BK=32, 256 thr (4 waves in 2x2)
//    fused: bf16 vcat write + atomic rowwise sum-of-squares into vnorm2[m]
__global__ void k_gemm1(const unsigned short* __restrict__ At,
                        const unsigned short* __restrict__ Wt,
                        const float* __restrict__ vsums, const float* __restrict__ csW,
                        const float* __restrict__ bv,
                        unsigned short* __restrict__ vcat, float* __restrict__ vnorm2) {
  __shared__ alignas(16) unsigned short sA[128 * 32];
  __shared__ alignas(16) unsigned short sB[128 * 32];
  const int tid = threadIdx.x;
  const int wave = tid >> 6, lane = tid & 63;
  const int quad = lane >> 4, l16 = lane & 15;
  const int m0 = blockIdx.x * 128, n0 = blockIdx.y * 128;
  const int wm = (wave & 1) * 64, wn = (wave >> 1) * 64;

  f32x4 acc[4][4];
#pragma unroll
  for (int i = 0; i < 4; i++)
#pragma unroll
    for (int j = 0; j < 4; j++) acc[i][j] = f32x4{0.f, 0.f, 0.f, 0.f};

  const int rowA0 = (wave * 2 + 0) * 16 + (lane >> 2);
  const int rowA1 = (wave * 2 + 1) * 16 + (lane >> 2);
  const int kk = (lane & 3) * 8;
  const unsigned short* gA0 = At + (size_t)(m0 + rowA0) * CDIM + kk;
  const unsigned short* gA1 = At + (size_t)(m0 + rowA1) * CDIM + kk;
  const unsigned short* gB0 = Wt + (size_t)(n0 + rowA0) * CDIM + kk;
  const unsigned short* gB1 = Wt + (size_t)(n0 + rowA1) * CDIM + kk;
  unsigned short* lA0 = &sA[(wave * 2 + 0) * 512];
  unsigned short* lA1 = &sA[(wave * 2 + 1) * 512];
  unsigned short* lB0 = &sB[(wave * 2 + 0) * 512];
  unsigned short* lB1 = &sB[(wave * 2 + 1) * 512];

  for (int kt = 0; kt < 32; ++kt) {
    const int koff = kt * 32;
    gload16(gA0 + koff, lA0);
    gload16(gA1 + koff, lA1);
    gload16(gB0 + koff, lB0);
    gload16(gB1 + koff, lB1);
    __syncthreads();
    bf16x8 aF[4], bF[4];
#pragma unroll
    for (int i = 0; i < 4; i++)
      aF[i] = *reinterpret_cast<const bf16x8*>(&sA[(wm + i * 16 + l16) * 32 + quad * 8]);
#pragma unroll
    for (int j = 0; j < 4; j++)
      bF[j] = *reinterpret_cast<const bf16x8*>(&sB[(wn + j * 16 + l16) * 32 + quad * 8]);
#pragma unroll
    for (int i = 0; i < 4; i++)
#pragma unroll
      for (int j = 0; j < 4; j++)
        acc[i][j] = __builtin_amdgcn_mfma_f32_16x16x32_bf16(aF[i], bF[j], acc[i][j], 0, 0, 0);
    __syncthreads();
  }

  // epilogue: centering correction, bf16 store, fused row sum-of-squares
  const float inv1024 = 1.f / 1024.f;
#pragma unroll
  for (int i = 0; i < 4; i++) {
    const int rbase = m0 + wm + i * 16 + quad * 4;   // 4 consecutive rows
    const float4 vs = *reinterpret_cast<const float4*>(&vsums[rbase]);
    const float mu[4] = {vs.x * inv1024, vs.y * inv1024, vs.z * inv1024, vs.w * inv1024};
    float ss[4] = {0.f, 0.f, 0.f, 0.f};
#pragma unroll
    for (int j = 0; j < 4; j++) {
      const int col = n0 + wn + j * 16 + l16;
      const float cs = csW[col];
      const float bb = bv[col];
#pragma unroll
      for (int r = 0; r < 4; r++) {
        const float val = acc[i][j][r] - mu[r] * cs + bb;
        vcat[(size_t)(rbase + r) * CDIM + col] = f2bf(val);
        ss[r] += val * val;
      }
    }
#pragma unroll
    for (int r = 0; r < 4; r++) {
      float v = ss[r];
      v += __shfl_xor(v, 1); v += __shfl_xor(v, 2);
      v += __shfl_xor(v, 4); v += __shfl_xor(v, 8);
      if (l16 == 0) atomicAdd(&vnorm2[rbase + r], v);
    }
  }
}

// ---------------------------------------------------------------------------
// 6) GEMM2: sim[s][m] = (scat[s]·vcat[m]) / (max(|vcat_m|,eps)*max(|scat_s|,eps))
//    tile 64(s) x 128(m), K=1024; fused mask + positive_map write
__global__ void k_gemm2(const unsigned short* __restrict__ scat,
                        const unsigned short* __restrict__ vcat,
                        const float* __restrict__ snorm2, const float* __restrict__ vnorm2,
                        const int* __restrict__ mask,
                        float* __restrict__ sim, float* __restrict__ pm) {
  __shared__ alignas(16) unsigned short sS[64 * 32];
  __shared__ alignas(16) unsigned short sV[128 * 32];
  const int tid = threadIdx.x;
  const int wave = tid >> 6, lane = tid & 63;
  const int quad = lane >> 4, l16 = lane & 15;
  const int m0 = blockIdx.x * 128;

  f32x4 acc[4][2];
#pragma unroll
  for (int i = 0; i < 4; i++)
#pragma unroll
    for (int j = 0; j < 2; j++) acc[i][j] = f32x4{0.f, 0.f, 0.f, 0.f};

  const int rS = wave * 16 + (lane >> 2);
  const int rV0 = (wave * 2 + 0) * 16 + (lane >> 2);
  const int rV1 = (wave * 2 + 1) * 16 + (lane >> 2);
  const int kk = (lane & 3) * 8;
  const unsigned short* gS = scat + (size_t)rS * CDIM + kk;
  const unsigned short* gV0 = vcat + (size_t)(m0 + rV0) * CDIM + kk;
  const unsigned short* gV1 = vcat + (size_t)(m0 + rV1) * CDIM + kk;
  unsigned short* lS = &sS[wave * 512];
  unsigned short* lV0 = &sV[(wave * 2 + 0) * 512];
  unsigned short* lV1 = &sV[(wave * 2 + 1) * 512];

  for (int kt = 0; kt < 32; ++kt) {
    const int koff = kt * 32;
    gload16(gS + koff, lS);
    gload16(gV0 + koff, lV0);
    gload16(gV1 + koff, lV1);
    __syncthreads();
    bf16x8 aF[4], bF[2];
#pragma unroll
    for (int i = 0; i < 4; i++)
      aF[i] = *reinterpret_cast<const bf16x8*>(&sS[(i * 16 + l16) * 32 + quad * 8]);
#pragma unroll
    for (int j = 0; j < 2; j++)
      bF[j] = *reinterpret_cast<const bf16x8*>(&sV[(wave * 32 + j * 16 + l16) * 32 + quad * 8]);
#pragma unroll
    for (int i = 0; i < 4; i++)
#pragma unroll
      for (int j = 0; j < 2; j++)
        acc[i][j] = __builtin_amdgcn_mfma_f32_16x16x32_bf16(aF[i], bF[j], acc[i][j], 0, 0, 0);
    __syncthreads();
  }

  const int b0 = m0 >> 10;   // batch index of this m-chunk (uniform per block)
#pragma unroll
  for (int j = 0; j < 2; j++) {
    const int m = m0 + wave * 32 + j * 16 + l16;
    const float vn = fmaxf(sqrtf(vnorm2[m]), 1e-8f);
    const int mk = mask[m];
#pragma unroll
    for (int i = 0; i < 4; i++) {
#pragma unroll
      for (int r = 0; r < 4; r++) {
        const int s = i * 16 + quad * 4 + r;
        const float sn = fmaxf(sqrtf(snorm2[s]), 1e-8f);
        float val = acc[i][j][r] / (vn * sn);
        if (mk == 0) val = -__builtin_inff();
        sim[(size_t)s * MDIM + m] = val;
        if (s == b0) pm[m] = val;
      }
    }
  }
}

// ---------------------------------------------------------------------------
// 7) per-(s,b): top-50 of sim row, IoU penalty, score — ONE WAVE per (s,b)
//    wave-synchronous iterative argmax over 16 regs/lane, zero barriers in loop
// grid (1024), 256 thr (4 waves)
__global__ void k_topk(const float* __restrict__ sim, const float* __restrict__ iou,
                       const float* __restrict__ lam, float* __restrict__ scores) {
  const int wave = threadIdx.x >> 6, lane = threadIdx.x & 63;
  const int sb = blockIdx.x * 4 + wave;
  const int s = sb >> 6, b = sb & 63;
  __shared__ float tvs[4][VNUM];
  __shared__ int tis[4][VNUM];

  const float* row = sim + (size_t)s * MDIM + (size_t)b * 1024;
  float v[16];
#pragma unroll
  for (int j = 0; j < 16; j++) v[j] = row[j * 64 + lane];   // strided: idx = j*64+lane

  for (int k = 0; k < VNUM; k++) {
    // local argmax over 16 registers (lowest j wins ties -> lowest global idx)
    float bv = v[0]; int bj = 0;
#pragma unroll
    for (int j = 1; j < 16; j++)
      if (v[j] > bv) { bv = v[j]; bj = j; }
    int bidx = bj * 64 + lane;
    // butterfly argmax across the wave (tie-break: lowest index)
#pragma unroll
    for (int o = 1; o < 64; o <<= 1) {
      const float ov = __shfl_xor(bv, o);
      const int oi = __shfl_xor(bidx, o);
      if (ov > bv || (ov == bv && oi < bidx)) { bv = ov; bidx = oi; }
    }
    if (lane == 0) { tvs[wave][k] = bv; tis[wave][k] = bidx; }
    // invalidate winner (bidx is wave-uniform; owner lane = bidx&63, reg = bidx>>6)
    const int wj = bidx >> 6;
    const bool mine = (bidx & 63) == lane;
#pragma unroll
    for (int j = 0; j < 16; j++)
      if (mine && wj == j) v[j] = -__builtin_inff();
  }
  __syncthreads();   // publish tvs/tis (cross-lane LDS reads below)

  // penalty: lane k (<50) owns column k: pen[k] = sum_{l>k} iou[idx_l][idx_k]^2
  float contrib = 0.f;
  if (lane < VNUM) {
    const int myidx = tis[wave][lane];
    float pen = 0.f;
    for (int l = lane + 1; l < VNUM; l++) {
      const float u = iou[(size_t)tis[wave][l] * 1024 + myidx];
      pen += u * u;
    }
    contrib = tvs[wave][lane] * expf(-pen / lam[0]);
  }
#pragma unroll
  for (int o = 32; o; o >>= 1) contrib += __shfl_down(contrib, o);
  if (lane == 0) scores[s * 64 + b] = contrib * (1.f / VNUM);
}

// ---------------------------------------------------------------------------
// 8) final 64x64 loss reduction
__global__ void k_loss(const float* __restrict__ scores, float* __restrict__ out) {
  __shared__ float S[64 * 64];
  __shared__ float diag[64];
  __shared__ float rmax[64], cmax[64];
  const int tid = threadIdx.x;
#pragma unroll
  for (int q = 0; q < 16; q++) S[tid + q * 256] = scores[tid + q * 256];
  __syncthreads();
  if (tid < 64) diag[tid] = S[tid * 64 + tid];
  __syncthreads();
  if (tid < 64) {
    float rm = 0.f, cm = 0.f;
    for (int x = 0; x < 64; x++) {
      if (x != tid) {
        const float cs = 0.2f + S[tid * 64 + x] - diag[tid];  // cost_s row tid
        rm = fmaxf(rm, fmaxf(cs, 0.f));
        const float ci = 0.2f + S[x * 64 + tid] - diag[tid];  // cost_im col tid
        cm = fmaxf(cm, fmaxf(ci, 0.f));
      }
    }
    rmax[tid] = rm; cmax[tid] = cm;
  }
  __syncthreads();
  if (tid == 0) {
    float L = 0.f;
    for (int t = 0; t < 64; t++) L += rmax[t] + cmax[t];
    out[0] = L * (1.f / 64.f);
  }
}

// ---------------------------------------------------------------------------
extern "C" void kernel_launch(void* const* d_in, const int* in_sizes, int n_in,
                              void* d_out, int out_size, void* d_ws, size_t ws_size,
                              hipStream_t stream) {
  (void)in_sizes; (void)n_in; (void)out_size; (void)ws_size;
  const float* videos = (const float*)d_in[0];
  const float* sent   = (const float*)d_in[1];
  const float* lam    = (const float*)d_in[2];
  const int*   mask   = (const int*)d_in[3];
  const float* iou    = (const float*)d_in[4];
  const float* W_v    = (const float*)d_in[6];
  const float* b_v    = (const float*)d_in[7];
  const float* W_s    = (const float*)d_in[8];
  const float* b_s    = (const float*)d_in[9];
  float* out = (float*)d_out;

  char* ws = (char*)d_ws;
  unsigned short* At   = (unsigned short*)(ws + 0);           // 128 MB
  unsigned short* vcat = (unsigned short*)(ws + 134217728);   // 128 MB
  float* sim           = (float*)(ws + 268435456);            // 16 MB
  unsigned short* Wt   = (unsigned short*)(ws + 285212672);   // 2 MB
  unsigned short* scat = (unsigned short*)(ws + 287309824);   // 128 KB
  float* vsums         = (float*)(ws + 287440896);            // 256 KB
  float* vnorm2        = (float*)(ws + 287703040);            // 256 KB
  float* snorm2        = (float*)(ws + 287965184);            // 256 B
  float* csW           = (float*)(ws + 287965440);            // 4 KB
  float* scores        = (float*)(ws + 287969536);            // 16 KB

  // zero vsums + vnorm2 + snorm2 (contiguous block)
  hipMemsetAsync(vsums, 0, 262144 + 262144 + 256, stream);

  k_transpose_videos<<<dim3(32, 32, 64), 256, 0, stream>>>(videos, At, vsums);
  k_transpose_W<<<dim3(8, 32, 4), 256, 0, stream>>>(W_v, Wt);
  k_row_sums<<<256, 256, 0, stream>>>(Wt, csW, 1024);
  k_scat<<<dim3(64, 4), 256, 0, stream>>>(sent, W_s, b_s, scat, snorm2);
  k_gemm1<<<dim3(512, 8), 256, 0, stream>>>(At, Wt, vsums, csW, b_v, vcat, vnorm2);
  k_gemm2<<<dim3(512), 256, 0, stream>>>(scat, vcat, snorm2, vnorm2, mask, sim, out + 1);
  k_topk<<<dim3(1024), 256, 0, stream>>>(sim, iou, lam, scores);
  k_loss<<<1, 256, 0, stream>>>(scores, out);
}

// Round 3
// 742.938 us; speedup vs baseline: 1.2221x; 1.0993x over previous
//
#include <hip/hip_runtime.h>
#include <cstdint>
#include <cstddef>

// Problem constants (static shapes from the reference)
#define CDIM  1024      // C
#define DTDIM 1024      // D*T
#define MDIM  65536     // B * D * T
#define BDIM  64        // B (batch / sentences)
#define VNUM  50        // valid_num

typedef __attribute__((ext_vector_type(8))) short bf16x8;
typedef __attribute__((ext_vector_type(4))) float f32x4;

__device__ __forceinline__ float bf2f(unsigned int u16) {
  return __uint_as_float(u16 << 16);
}
__device__ __forceinline__ unsigned short f2bf(float x) {
  unsigned int u = __float_as_uint(x);
  u += 0x7fffu + ((u >> 16) & 1u);   // round-to-nearest-even
  return (unsigned short)(u >> 16);
}

// async global -> LDS, 16B per lane; LDS dest is wave-uniform base + lane*16
__device__ __forceinline__ void gload16(const void* g, void* l) {
  __builtin_amdgcn_global_load_lds((const __attribute__((address_space(1))) void*)g,
                                   (__attribute__((address_space(3))) void*)l,
                                   16, 0, 0);
}

// ---------------------------------------------------------------------------
// 1) videos fp32 [b][c][dt] -> At bf16 [b*1024+dt][c]  (64x64 LDS transpose)
//    float4 loads, packed 2xbf16 stores, fused per-(b,dt) row sums
// grid (16 dt-tiles, 16 c-tiles, 64 b), 256 thr
__global__ void k_transpose_videos(const float* __restrict__ vid,
                                   unsigned short* __restrict__ At,
                                   float* __restrict__ vsums) {
  __shared__ float t[64][65];
  const int tid = threadIdx.x;
  const int dt0 = blockIdx.x * 64, c0 = blockIdx.y * 64, b = blockIdx.z;
  const int lc = tid >> 4;          // 0..15 (c-row within pass)
  const int l4 = (tid & 15) * 4;    // dt offset (float4)
  const float* src = vid + ((size_t)b * CDIM + c0) * DTDIM + dt0;
#pragma unroll
  for (int p = 0; p < 4; p++) {
    const int c = p * 16 + lc;
    const float4 f = *reinterpret_cast<const float4*>(&src[(size_t)c * DTDIM + l4]);
    t[c][l4 + 0] = f.x; t[c][l4 + 1] = f.y; t[c][l4 + 2] = f.z; t[c][l4 + 3] = f.w;
  }
  __syncthreads();
  const int dr = tid >> 5;          // 0..7 (dt-row within pass)
  const int cl = tid & 31;          // c-pair index
  unsigned int* dstbase = reinterpret_cast<unsigned int*>(
      At + ((size_t)(b * DTDIM + dt0)) * CDIM + c0);
#pragma unroll
  for (int p = 0; p < 8; p++) {
    const int dt = p * 8 + dr;
    const float a0 = t[2 * cl][dt], a1 = t[2 * cl + 1][dt];
    const unsigned int u = (unsigned int)f2bf(a0) | ((unsigned int)f2bf(a1) << 16);
    dstbase[(size_t)dt * 512 + cl] = u;
    float s = a0 + a1;
    s += __shfl_xor(s, 1);  s += __shfl_xor(s, 2);  s += __shfl_xor(s, 4);
    s += __shfl_xor(s, 8);  s += __shfl_xor(s, 16);
    if (cl == 0) atomicAdd(&vsums[(size_t)b * DTDIM + dt0 + dt], s);
  }
}

// ---------------------------------------------------------------------------
// 2) W_v fp32 [kb][c][f] -> Wt bf16 [kb*256+f][c]
// grid (8 f-tiles, 32 c-tiles, 4 kb), 256 thr
__global__ void k_transpose_W(const float* __restrict__ W,
                              unsigned short* __restrict__ Wt) {
  __shared__ float t[32][33];
  const int tx = threadIdx.x & 31, ty = threadIdx.x >> 5;
  const int f0 = blockIdx.x * 32, c0 = blockIdx.y * 32, kb = blockIdx.z;
  const float* src = W + ((size_t)kb * CDIM + c0) * 256 + f0;
#pragma unroll
  for (int i = 0; i < 4; i++) {
    const int cl = ty + i * 8;
    t[cl][tx] = src[(size_t)cl * 256 + tx];
  }
  __syncthreads();
  unsigned short* dst = Wt + ((size_t)(kb * 256 + f0)) * CDIM + c0;
#pragma unroll
  for (int i = 0; i < 4; i++) {
    const int fl = ty + i * 8;
    dst[(size_t)fl * CDIM + tx] = f2bf(t[tx][fl]);
  }
}

// ---------------------------------------------------------------------------
// 3) per-row fp32 sums of a bf16 [nrows][1024] matrix (one wave per row)
__global__ void k_row_sums(const unsigned short* __restrict__ A,
                           float* __restrict__ out, int nrows) {
  const int wave = threadIdx.x >> 6, lane = threadIdx.x & 63;
  const int row = blockIdx.x * 4 + wave;
  if (row >= nrows) return;
  const unsigned short* r = A + (size_t)row * 1024;
  float s = 0.f;
#pragma unroll
  for (int h = 0; h < 2; h++) {
    const uint4 u = *reinterpret_cast<const uint4*>(r + h * 512 + lane * 8);
    s += bf2f(u.x & 0xffffu) + bf2f(u.x >> 16);
    s += bf2f(u.y & 0xffffu) + bf2f(u.y >> 16);
    s += bf2f(u.z & 0xffffu) + bf2f(u.z >> 16);
    s += bf2f(u.w & 0xffffu) + bf2f(u.w >> 16);
  }
#pragma unroll
  for (int o = 32; o; o >>= 1) s += __shfl_down(s, o);
  if (lane == 0) out[row] = s;
}

// ---------------------------------------------------------------------------
// 4) sentence projection (fp32)
// grid (64 s, 4 j), 256 thr
__global__ void k_scat(const float* __restrict__ sent, const float* __restrict__ Ws,
                       const float* __restrict__ bs, unsigned short* __restrict__ scat,
                       float* __restrict__ snorm2) {
  const int s = blockIdx.x, j = blockIdx.y, tid = threadIdx.x;
  __shared__ float sc[1024];
  __shared__ float red[4];
  float p = 0.f;
#pragma unroll
  for (int q = 0; q < 4; q++) {
    const float x = sent[(size_t)s * 1024 + tid + q * 256];
    sc[tid + q * 256] = x;
    p += x;
  }
#pragma unroll
  for (int o = 32; o; o >>= 1) p += __shfl_down(p, o);
  const int wave = tid >> 6, lane = tid & 63;
  if (lane == 0) red[wave] = p;
  __syncthreads();
  const float mean = (red[0] + red[1] + red[2] + red[3]) * (1.f / 1024.f);
  float acc = 0.f;
  const float* W = Ws + ((size_t)j * 1024) * 256 + tid;
  for (int c = 0; c < 1024; c++) acc += (sc[c] - mean) * W[(size_t)c * 256];
  const int n = j * 256 + tid;
  const float val = acc + bs[n];
  scat[(size_t)s * 1024 + n] = f2bf(val);
  float v2 = val * val;
#pragma unroll
  for (int o = 32; o; o >>= 1) v2 += __shfl_down(v2, o);
  if (lane == 0) atomicAdd(&snorm2[s], v2);
}

// ---------------------------------------------------------------------------
// 5) GEMM1: vcat[m][n] = sum_k At[m][k]*Wt[n][k] - mu[m]*csW[n] + bv[n]
//    1-D grid with locality swizzle: 64 consecutive ids = 8 m-tiles x all 8 n-tiles
//    LDS XOR swizzle (chunk' = chunk ^ ((row>>1)&3)) kills ds_read_b128 conflicts
__global__ void k_gemm1(const unsigned short* __restrict__ At,
                        const unsigned short* __restrict__ Wt,
                        const float* __restrict__ vsums, const float* __restrict__ csW,
                        const float* __restrict__ bv,
                        unsigned short* __restrict__ vcat, float* __restrict__ vnorm2) {
  __shared__ alignas(16) unsigned short sA[128 * 32];
  __shared__ alignas(16) unsigned short sB[128 * 32];
  const int tid = threadIdx.x;
  const int wave = tid >> 6, lane = tid & 63;
  const int quad = lane >> 4, l16 = lane & 15;
  const int id = blockIdx.x;
  const int m0 = (((id >> 6) << 3) + (id & 7)) * 128;   // m-tile: bits[11:6]*8 + bits[2:0]
  const int n0 = ((id >> 3) & 7) * 128;                 // n-tile: bits[5:3]
  const int wm = (wave & 1) * 64, wn = (wave >> 1) * 64;

  f32x4 acc[4][4];
#pragma unroll
  for (int i = 0; i < 4; i++)
#pragma unroll
    for (int j = 0; j < 4; j++) acc[i][j] = f32x4{0.f, 0.f, 0.f, 0.f};

  // staging: row-in-group r = lane>>2, source chunk XOR-swizzled by (r>>1)&3
  const int r = lane >> 2;
  const int kk = (((lane & 3) ^ ((r >> 1) & 3)) * 8);
  const int rowA0 = (wave * 2 + 0) * 16 + r;
  const int rowA1 = (wave * 2 + 1) * 16 + r;
  const unsigned short* gA0 = At + (size_t)(m0 + rowA0) * CDIM + kk;
  const unsigned short* gA1 = At + (size_t)(m0 + rowA1) * CDIM + kk;
  const unsigned short* gB0 = Wt + (size_t)(n0 + rowA0) * CDIM + kk;
  const unsigned short* gB1 = Wt + (size_t)(n0 + rowA1) * CDIM + kk;
  unsigned short* lA0 = &sA[(wave * 2 + 0) * 512];
  unsigned short* lA1 = &sA[(wave * 2 + 1) * 512];
  unsigned short* lB0 = &sB[(wave * 2 + 0) * 512];
  unsigned short* lB1 = &sB[(wave * 2 + 1) * 512];

  const int sw = (l16 >> 1) & 3;   // fragment-read swizzle

  for (int kt = 0; kt < 32; ++kt) {
    const int koff = kt * 32;
    gload16(gA0 + koff, lA0);
    gload16(gA1 + koff, lA1);
    gload16(gB0 + koff, lB0);
    gload16(gB1 + koff, lB1);
    __syncthreads();
    bf16x8 aF[4], bF[4];
#pragma unroll
    for (int i = 0; i < 4; i++)
      aF[i] = *reinterpret_cast<const bf16x8*>(
          &sA[(wm + i * 16 + l16) * 32 + ((quad ^ sw) * 8)]);
#pragma unroll
    for (int j = 0; j < 4; j++)
      bF[j] = *reinterpret_cast<const bf16x8*>(
          &sB[(wn + j * 16 + l16) * 32 + ((quad ^ sw) * 8)]);
#pragma unroll
    for (int i = 0; i < 4; i++)
#pragma unroll
      for (int j = 0; j < 4; j++)
        acc[i][j] = __builtin_amdgcn_mfma_f32_16x16x32_bf16(aF[i], bF[j], acc[i][j], 0, 0, 0);
    __syncthreads();
  }

  // epilogue: centering correction, bf16 store, fused row sum-of-squares
  const float inv1024 = 1.f / 1024.f;
#pragma unroll
  for (int i = 0; i < 4; i++) {
    const int rbase = m0 + wm + i * 16 + quad * 4;   // 4 consecutive rows
    const float4 vs = *reinterpret_cast<const float4*>(&vsums[rbase]);
    const float mu[4] = {vs.x * inv1024, vs.y * inv1024, vs.z * inv1024, vs.w * inv1024};
    float ss[4] = {0.f, 0.f, 0.f, 0.f};
#pragma unroll
    for (int j = 0; j < 4; j++) {
      const int col = n0 + wn + j * 16 + l16;
      const float cs = csW[col];
      const float bb = bv[col];
#pragma unroll
      for (int rr = 0; rr < 4; rr++) {
        const float val = acc[i][j][rr] - mu[rr] * cs + bb;
        vcat[(size_t)(rbase + rr) * CDIM + col] = f2bf(val);
        ss[rr] += val * val;
      }
    }
#pragma unroll
    for (int rr = 0; rr < 4; rr++) {
      float v = ss[rr];
      v += __shfl_xor(v, 1); v += __shfl_xor(v, 2);
      v += __shfl_xor(v, 4); v += __shfl_xor(v, 8);
      if (l16 == 0) atomicAdd(&vnorm2[rbase + rr], v);
    }
  }
}

// ---------------------------------------------------------------------------
// 6) GEMM2: sim[s][m] with fused normalize + mask + positive_map
__global__ void k_gemm2(const unsigned short* __restrict__ scat,
                        const unsigned short* __restrict__ vcat,
                        const float* __restrict__ snorm2, const float* __restrict__ vnorm2,
                        const int* __restrict__ mask,
                        float* __restrict__ sim, float* __restrict__ pm) {
  __shared__ alignas(16) unsigned short sS[64 * 32];
  __shared__ alignas(16) unsigned short sV[128 * 32];
  const int tid = threadIdx.x;
  const int wave = tid >> 6, lane = tid & 63;
  const int quad = lane >> 4, l16 = lane & 15;
  const int m0 = blockIdx.x * 128;

  f32x4 acc[4][2];
#pragma unroll
  for (int i = 0; i < 4; i++)
#pragma unroll
    for (int j = 0; j < 2; j++) acc[i][j] = f32x4{0.f, 0.f, 0.f, 0.f};

  const int r = lane >> 2;
  const int kk = (((lane & 3) ^ ((r >> 1) & 3)) * 8);
  const int rS = wave * 16 + r;
  const int rV0 = (wave * 2 + 0) * 16 + r;
  const int rV1 = (wave * 2 + 1) * 16 + r;
  const unsigned short* gS = scat + (size_t)rS * CDIM + kk;
  const unsigned short* gV0 = vcat + (size_t)(m0 + rV0) * CDIM + kk;
  const unsigned short* gV1 = vcat + (size_t)(m0 + rV1) * CDIM + kk;
  unsigned short* lS = &sS[wave * 512];
  unsigned short* lV0 = &sV[(wave * 2 + 0) * 512];
  unsigned short* lV1 = &sV[(wave * 2 + 1) * 512];

  const int sw = (l16 >> 1) & 3;

  for (int kt = 0; kt < 32; ++kt) {
    const int koff = kt * 32;
    gload16(gS + koff, lS);
    gload16(gV0 + koff, lV0);
    gload16(gV1 + koff, lV1);
    __syncthreads();
    bf16x8 aF[4], bF[2];
#pragma unroll
    for (int i = 0; i < 4; i++)
      aF[i] = *reinterpret_cast<const bf16x8*>(
          &sS[(i * 16 + l16) * 32 + ((quad ^ sw) * 8)]);
#pragma unroll
    for (int j = 0; j < 2; j++)
      bF[j] = *reinterpret_cast<const bf16x8*>(
          &sV[(wave * 32 + j * 16 + l16) * 32 + ((quad ^ sw) * 8)]);
#pragma unroll
    for (int i = 0; i < 4; i++)
#pragma unroll
      for (int j = 0; j < 2; j++)
        acc[i][j] = __builtin_amdgcn_mfma_f32_16x16x32_bf16(aF[i], bF[j], acc[i][j], 0, 0, 0);
    __syncthreads();
  }

  const int b0 = m0 >> 10;   // batch index of this m-chunk (uniform per block)
#pragma unroll
  for (int j = 0; j < 2; j++) {
    const int m = m0 + wave * 32 + j * 16 + l16;
    const float vn = fmaxf(sqrtf(vnorm2[m]), 1e-8f);
    const int mk = mask[m];
#pragma unroll
    for (int i = 0; i < 4; i++) {
#pragma unroll
      for (int rr = 0; rr < 4; rr++) {
        const int s = i * 16 + quad * 4 + rr;
        const float sn = fmaxf(sqrtf(snorm2[s]), 1e-8f);
        float val = acc[i][j][rr] / (vn * sn);
        if (mk == 0) val = -__builtin_inff();
        sim[(size_t)s * MDIM + m] = val;
        if (s == b0) pm[m] = val;
      }
    }
  }
}

// ---------------------------------------------------------------------------
// 7) per-(s,b): top-50, IoU penalty, score — ONE WAVE per (s,b), zero barriers
// grid (1024), 256 thr (4 waves)
__global__ void k_topk(const float* __restrict__ sim, const float* __restrict__ iou,
                       const float* __restrict__ lam, float* __restrict__ scores) {
  const int wave = threadIdx.x >> 6, lane = threadIdx.x & 63;
  const int sb = blockIdx.x * 4 + wave;
  const int s = sb >> 6, b = sb & 63;
  __shared__ float tvs[4][VNUM];
  __shared__ int tis[4][VNUM];

  const float* row = sim + (size_t)s * MDIM + (size_t)b * 1024;
  float v[16];
#pragma unroll
  for (int j = 0; j < 16; j++) v[j] = row[j * 64 + lane];

  for (int k = 0; k < VNUM; k++) {
    float bv = v[0]; int bj = 0;
#pragma unroll
    for (int j = 1; j < 16; j++)
      if (v[j] > bv) { bv = v[j]; bj = j; }
    int bidx = bj * 64 + lane;
#pragma unroll
    for (int o = 1; o < 64; o <<= 1) {
      const float ov = __shfl_xor(bv, o);
      const int oi = __shfl_xor(bidx, o);
      if (ov > bv || (ov == bv && oi < bidx)) { bv = ov; bidx = oi; }
    }
    if (lane == 0) { tvs[wave][k] = bv; tis[wave][k] = bidx; }
    const int wj = bidx >> 6;
    const bool mine = (bidx & 63) == lane;
#pragma unroll
    for (int j = 0; j < 16; j++)
      if (mine && wj == j) v[j] = -__builtin_inff();
  }
  __syncthreads();

  float contrib = 0.f;
  if (lane < VNUM) {
    const int myidx = tis[wave][lane];
    float pen = 0.f;
    for (int l = lane + 1; l < VNUM; l++) {
      const float u = iou[(size_t)tis[wave][l] * 1024 + myidx];
      pen += u * u;
    }
    contrib = tvs[wave][lane] * expf(-pen / lam[0]);
  }
#pragma unroll
  for (int o = 32; o; o >>= 1) contrib += __shfl_down(contrib, o);
  if (lane == 0) scores[s * 64 + b] = contrib * (1.f / VNUM);
}

// ---------------------------------------------------------------------------
// 8) final 64x64 loss reduction
__global__ void k_loss(const float* __restrict__ scores, float* __restrict__ out) {
  __shared__ float S[64 * 64];
  __shared__ float diag[64];
  __shared__ float rmax[64], cmax[64];
  const int tid = threadIdx.x;
#pragma unroll
  for (int q = 0; q < 16; q++) S[tid + q * 256] = scores[tid + q * 256];
  __syncthreads();
  if (tid < 64) diag[tid] = S[tid * 64 + tid];
  __syncthreads();
  if (tid < 64) {
    float rm = 0.f, cm = 0.f;
    for (int x = 0; x < 64; x++) {
      if (x != tid) {
        const float cs = 0.2f + S[tid * 64 + x] - diag[tid];
        rm = fmaxf(rm, fmaxf(cs, 0.f));
        const float ci = 0.2f + S[x * 64 + tid] - diag[tid];
        cm = fmaxf(cm, fmaxf(ci, 0.f));
      }
    }
    rmax[tid] = rm; cmax[tid] = cm;
  }
  __syncthreads();
  if (tid == 0) {
    float L = 0.f;
    for (int t = 0; t < 64; t++) L += rmax[t] + cmax[t];
    out[0] = L * (1.f / 64.f);
  }
}

// ---------------------------------------------------------------------------
extern "C" void kernel_launch(void* const* d_in, const int* in_sizes, int n_in,
                              void* d_out, int out_size, void* d_ws, size_t ws_size,
                              hipStream_t stream) {
  (void)in_sizes; (void)n_in; (void)out_size; (void)ws_size;
  const float* videos = (const float*)d_in[0];
  const float* sent   = (const float*)d_in[1];
  const float* lam    = (const float*)d_in[2];
  const int*   mask   = (const int*)d_in[3];
  const float* iou    = (const float*)d_in[4];
  const float* W_v    = (const float*)d_in[6];
  const float* b_v    = (const float*)d_in[7];
  const float* W_s    = (const float*)d_in[8];
  const float* b_s    = (const float*)d_in[9];
  float* out = (float*)d_out;

  char* ws = (char*)d_ws;
  unsigned short* At   = (unsigned short*)(ws + 0);           // 128 MB
  unsigned short* vcat = (unsigned short*)(ws + 134217728);   // 128 MB
  float* sim           = (float*)(ws + 268435456);            // 16 MB
  unsigned short* Wt   = (unsigned short*)(ws + 285212672);   // 2 MB
  unsigned short* scat = (unsigned short*)(ws + 287309824);   // 128 KB
  float* vsums         = (float*)(ws + 287440896);            // 256 KB
  float* vnorm2        = (float*)(ws + 287703040);            // 256 KB
  float* snorm2        = (float*)(ws + 287965184);            // 256 B
  float* csW           = (float*)(ws + 287965440);            // 4 KB
  float* scores        = (float*)(ws + 287969536);            // 16 KB

  // zero vsums + vnorm2 + snorm2 (contiguous block)
  hipMemsetAsync(vsums, 0, 262144 + 262144 + 256, stream);

  k_transpose_videos<<<dim3(16, 16, 64), 256, 0, stream>>>(videos, At, vsums);
  k_transpose_W<<<dim3(8, 32, 4), 256, 0, stream>>>(W_v, Wt);
  k_row_sums<<<256, 256, 0, stream>>>(Wt, csW, 1024);
  k_scat<<<dim3(64, 4), 256, 0, stream>>>(sent, W_s, b_s, scat, snorm2);
  k_gemm1<<<dim3(4096), 256, 0, stream>>>(At, Wt, vsums, csW, b_v, vcat, vnorm2);
  k_gemm2<<<dim3(512), 256, 0, stream>>>(scat, vcat, snorm2, vnorm2, mask, sim, out + 1);
  k_topk<<<dim3(1024), 256, 0, stream>>>(sim, iou, lam, scores);
  k_loss<<<1, 256, 0, stream>>>(scores, out);
}

// Round 4
// 725.884 us; speedup vs baseline: 1.2508x; 1.0235x over previous
//
#include <hip/hip_runtime.h>
#include <cstdint>
#include <cstddef>

// Problem constants (static shapes from the reference)
#define CDIM  1024      // C
#define DTDIM 1024      // D*T
#define MDIM  65536     // B * D * T
#define BDIM  64        // B (batch / sentences)
#define VNUM  50        // valid_num

typedef __attribute__((ext_vector_type(8))) short bf16x8;
typedef __attribute__((ext_vector_type(4))) float f32x4;

__device__ __forceinline__ float bf2f(unsigned int u16) {
  return __uint_as_float(u16 << 16);
}
__device__ __forceinline__ unsigned short f2bf(float x) {
  unsigned int u = __float_as_uint(x);
  u += 0x7fffu + ((u >> 16) & 1u);   // round-to-nearest-even
  return (unsigned short)(u >> 16);
}

// async global -> LDS, 16B per lane; LDS dest is wave-uniform base + lane*16
__device__ __forceinline__ void gload16(const void* g, void* l) {
  __builtin_amdgcn_global_load_lds((const __attribute__((address_space(1))) void*)g,
                                   (__attribute__((address_space(3))) void*)l,
                                   16, 0, 0);
}

// ---------------------------------------------------------------------------
// 1) videos fp32 [b][c][dt] -> At bf16 [b*1024+dt][c]  (64x64 LDS transpose)
//    float4 loads, packed 2xbf16 stores, fused per-(b,dt) row sums
// grid (16 dt-tiles, 16 c-tiles, 64 b), 256 thr
__global__ void k_transpose_videos(const float* __restrict__ vid,
                                   unsigned short* __restrict__ At,
                                   float* __restrict__ vsums) {
  __shared__ float t[64][65];
  const int tid = threadIdx.x;
  const int dt0 = blockIdx.x * 64, c0 = blockIdx.y * 64, b = blockIdx.z;
  const int lc = tid >> 4;          // 0..15 (c-row within pass)
  const int l4 = (tid & 15) * 4;    // dt offset (float4)
  const float* src = vid + ((size_t)b * CDIM + c0) * DTDIM + dt0;
#pragma unroll
  for (int p = 0; p < 4; p++) {
    const int c = p * 16 + lc;
    const float4 f = *reinterpret_cast<const float4*>(&src[(size_t)c * DTDIM + l4]);
    t[c][l4 + 0] = f.x; t[c][l4 + 1] = f.y; t[c][l4 + 2] = f.z; t[c][l4 + 3] = f.w;
  }
  __syncthreads();
  const int dr = tid >> 5;          // 0..7 (dt-row within pass)
  const int cl = tid & 31;          // c-pair index
  unsigned int* dstbase = reinterpret_cast<unsigned int*>(
      At + ((size_t)(b * DTDIM + dt0)) * CDIM + c0);
#pragma unroll
  for (int p = 0; p < 8; p++) {
    const int dt = p * 8 + dr;
    const float a0 = t[2 * cl][dt], a1 = t[2 * cl + 1][dt];
    const unsigned int u = (unsigned int)f2bf(a0) | ((unsigned int)f2bf(a1) << 16);
    dstbase[(size_t)dt * 512 + cl] = u;
    float s = a0 + a1;
    s += __shfl_xor(s, 1);  s += __shfl_xor(s, 2);  s += __shfl_xor(s, 4);
    s += __shfl_xor(s, 8);  s += __shfl_xor(s, 16);
    if (cl == 0) atomicAdd(&vsums[(size_t)b * DTDIM + dt0 + dt], s);
  }
}

// ---------------------------------------------------------------------------
// 2) W_v fp32 [kb][c][f] -> Wt bf16 [kb*256+f][c]
// grid (8 f-tiles, 32 c-tiles, 4 kb), 256 thr
__global__ void k_transpose_W(const float* __restrict__ W,
                              unsigned short* __restrict__ Wt) {
  __shared__ float t[32][33];
  const int tx = threadIdx.x & 31, ty = threadIdx.x >> 5;
  const int f0 = blockIdx.x * 32, c0 = blockIdx.y * 32, kb = blockIdx.z;
  const float* src = W + ((size_t)kb * CDIM + c0) * 256 + f0;
#pragma unroll
  for (int i = 0; i < 4; i++) {
    const int cl = ty + i * 8;
    t[cl][tx] = src[(size_t)cl * 256 + tx];
  }
  __syncthreads();
  unsigned short* dst = Wt + ((size_t)(kb * 256 + f0)) * CDIM + c0;
#pragma unroll
  for (int i = 0; i < 4; i++) {
    const int fl = ty + i * 8;
    dst[(size_t)fl * CDIM + tx] = f2bf(t[tx][fl]);
  }
}

// ---------------------------------------------------------------------------
// 3) per-row fp32 sums of a bf16 [nrows][1024] matrix (one wave per row)
__global__ void k_row_sums(const unsigned short* __restrict__ A,
                           float* __restrict__ out, int nrows) {
  const int wave = threadIdx.x >> 6, lane = threadIdx.x & 63;
  const int row = blockIdx.x * 4 + wave;
  if (row >= nrows) return;
  const unsigned short* r = A + (size_t)row * 1024;
  float s = 0.f;
#pragma unroll
  for (int h = 0; h < 2; h++) {
    const uint4 u = *reinterpret_cast<const uint4*>(r + h * 512 + lane * 8);
    s += bf2f(u.x & 0xffffu) + bf2f(u.x >> 16);
    s += bf2f(u.y & 0xffffu) + bf2f(u.y >> 16);
    s += bf2f(u.z & 0xffffu) + bf2f(u.z >> 16);
    s += bf2f(u.w & 0xffffu) + bf2f(u.w >> 16);
  }
#pragma unroll
  for (int o = 32; o; o >>= 1) s += __shfl_down(s, o);
  if (lane == 0) out[row] = s;
}

// ---------------------------------------------------------------------------
// 4) sentence projection (fp32)
// grid (64 s, 4 j), 256 thr
__global__ void k_scat(const float* __restrict__ sent, const float* __restrict__ Ws,
                       const float* __restrict__ bs, unsigned short* __restrict__ scat,
                       float* __restrict__ snorm2) {
  const int s = blockIdx.x, j = blockIdx.y, tid = threadIdx.x;
  __shared__ float sc[1024];
  __shared__ float red[4];
  float p = 0.f;
#pragma unroll
  for (int q = 0; q < 4; q++) {
    const float x = sent[(size_t)s * 1024 + tid + q * 256];
    sc[tid + q * 256] = x;
    p += x;
  }
#pragma unroll
  for (int o = 32; o; o >>= 1) p += __shfl_down(p, o);
  const int wave = tid >> 6, lane = tid & 63;
  if (lane == 0) red[wave] = p;
  __syncthreads();
  const float mean = (red[0] + red[1] + red[2] + red[3]) * (1.f / 1024.f);
  float acc = 0.f;
  const float* W = Ws + ((size_t)j * 1024) * 256 + tid;
  for (int c = 0; c < 1024; c++) acc += (sc[c] - mean) * W[(size_t)c * 256];
  const int n = j * 256 + tid;
  const float val = acc + bs[n];
  scat[(size_t)s * 1024 + n] = f2bf(val);
  float v2 = val * val;
#pragma unroll
  for (int o = 32; o; o >>= 1) v2 += __shfl_down(v2, o);
  if (lane == 0) atomicAdd(&snorm2[s], v2);
}

// ---------------------------------------------------------------------------
// 5) FUSED GEMM: per 128-row m-slab, loop 8 n-tiles:
//      K-loop (BK=64): vcat_tile = At_slab . Wt_tile^T  (MFMA, 16x16x32 bf16)
//      epilogue: centering+bias -> bf16 vtile in LDS (never to HBM), ss += val^2
//      MFMA2: P[s][m] += scat_tile . vtile^T  (contract this n-tile's 128 c)
//    final: vn from ss, sim[s][m] = P/(vn*sn), mask, pm write.  GEMM2 is gone.
// grid (512), 256 thr (4 waves, 2x2 over 128x128)
__global__ __launch_bounds__(256, 2) void k_gemm_fused(
    const unsigned short* __restrict__ At, const unsigned short* __restrict__ Wt,
    const float* __restrict__ vsums, const float* __restrict__ csW,
    const float* __restrict__ bv, const unsigned short* __restrict__ scat,
    const float* __restrict__ snorm2, const int* __restrict__ mask,
    float* __restrict__ sim, float* __restrict__ pm) {
  __shared__ alignas(16) char smem[32768 + 16384 + 256 + 1024];
  unsigned short* sAB   = (unsigned short*)smem;            // sA [0,16K), sB [16K,32K)
  unsigned short* vtile = (unsigned short*)smem;            // overlaps sA/sB (epilogue phase)
  unsigned short* stile = (unsigned short*)(smem + 32768);  // 64x128 scat chunk
  float* invSnLds       = (float*)(smem + 49152);           // 64
  float* vnLds          = (float*)(smem + 49152 + 256);     // 2 x 128

  const int tid = threadIdx.x;
  const int wave = tid >> 6, lane = tid & 63;
  const int quad = lane >> 4, l16 = lane & 15;
  const int m0 = blockIdx.x * 128;
  const int wm = (wave & 1) * 64, wn = (wave >> 1) * 64;

  if (tid < 64) invSnLds[tid] = 1.f / fmaxf(sqrtf(snorm2[tid]), 1e-8f);

  f32x4 acc2[4][2];
#pragma unroll
  for (int i = 0; i < 4; i++)
#pragma unroll
    for (int j = 0; j < 2; j++) acc2[i][j] = f32x4{0.f, 0.f, 0.f, 0.f};
  float ss[4][4];
#pragma unroll
  for (int i = 0; i < 4; i++)
#pragma unroll
    for (int rr = 0; rr < 4; rr++) ss[i][rr] = 0.f;

  const float inv1024 = 1.f / 1024.f;

  for (int nt = 0; nt < 8; ++nt) {
    const int n0 = nt * 128;

    // stage scat chunk [64 s][128 c] (XOR-swizzled 16B chunks, key = row&15)
#pragma unroll
    for (int ii = 0; ii < 4; ii++) {
      const int srow = (ii * 4 + wave) * 4 + (lane >> 4);
      const int g = (lane & 15) ^ (srow & 15);
      gload16(scat + (size_t)srow * 1024 + n0 + g * 8,
              stile + (ii * 4 + wave) * 512);
    }

    f32x4 acc[4][4];
#pragma unroll
    for (int i = 0; i < 4; i++)
#pragma unroll
      for (int j = 0; j < 4; j++) acc[i][j] = f32x4{0.f, 0.f, 0.f, 0.f};

    // K-loop, BK=64 (16 iters, half the barriers of BK=32)
    for (int kt = 0; kt < 16; ++kt) {
      const int koff = kt * 64;
#pragma unroll
      for (int ii = 0; ii < 4; ii++) {
        const int r = (ii * 4 + wave) * 8 + (lane >> 3);
        const int g = (lane & 7) ^ (r & 7);
        gload16(At + (size_t)(m0 + r) * CDIM + koff + g * 8,
                sAB + (ii * 4 + wave) * 512);
        gload16(Wt + (size_t)(n0 + r) * CDIM + koff + g * 8,
                sAB + 8192 + (ii * 4 + wave) * 512);
      }
      __syncthreads();
#pragma unroll
      for (int ks = 0; ks < 2; ks++) {
        const int slot = ((ks * 4 + quad) ^ (l16 & 7)) * 8;
        bf16x8 aF[4], bF[4];
#pragma unroll
        for (int i = 0; i < 4; i++)
          aF[i] = *reinterpret_cast<const bf16x8*>(&sAB[(wm + i * 16 + l16) * 64 + slot]);
#pragma unroll
        for (int j = 0; j < 4; j++)
          bF[j] = *reinterpret_cast<const bf16x8*>(&sAB[8192 + (wn + j * 16 + l16) * 64 + slot]);
#pragma unroll
        for (int i = 0; i < 4; i++)
#pragma unroll
          for (int j = 0; j < 4; j++)
            acc[i][j] = __builtin_amdgcn_mfma_f32_16x16x32_bf16(aF[i], bF[j], acc[i][j], 0, 0, 0);
      }
      __syncthreads();
    }

    // epilogue: centering+bias, bf16 into vtile (swizzled [m][c]), ss accumulate
#pragma unroll
    for (int i = 0; i < 4; i++) {
      const int rbase = wm + i * 16 + quad * 4;
      const float4 vs = *reinterpret_cast<const float4*>(&vsums[m0 + rbase]);
      const float mu[4] = {vs.x * inv1024, vs.y * inv1024, vs.z * inv1024, vs.w * inv1024};
#pragma unroll
      for (int j = 0; j < 4; j++) {
        const int c = wn + j * 16 + l16;
        const float cs = csW[n0 + c];
        const float bb = bv[n0 + c];
#pragma unroll
        for (int rr = 0; rr < 4; rr++) {
          const int m = rbase + rr;
          const float val = acc[i][j][rr] - mu[rr] * cs + bb;
          ss[i][rr] += val * val;
          const int slot = (c >> 3) ^ (m & 15);
          vtile[m * 128 + slot * 8 + (c & 7)] = f2bf(val);
        }
      }
    }
    __syncthreads();

    // MFMA2: P[s=64][m=128] += scat_chunk . vtile^T  (wave owns 32 m cols)
#pragma unroll
    for (int ks2 = 0; ks2 < 4; ks2++) {
      const int slot = ((ks2 * 4 + quad) ^ l16) * 8;
      bf16x8 a2[4], b2[2];
#pragma unroll
      for (int i2 = 0; i2 < 4; i2++)
        a2[i2] = *reinterpret_cast<const bf16x8*>(&stile[(i2 * 16 + l16) * 128 + slot]);
#pragma unroll
      for (int j2 = 0; j2 < 2; j2++)
        b2[j2] = *reinterpret_cast<const bf16x8*>(&vtile[(wave * 32 + j2 * 16 + l16) * 128 + slot]);
#pragma unroll
      for (int i2 = 0; i2 < 4; i2++)
#pragma unroll
        for (int j2 = 0; j2 < 2; j2++)
          acc2[i2][j2] = __builtin_amdgcn_mfma_f32_16x16x32_bf16(a2[i2], b2[j2], acc2[i2][j2], 0, 0, 0);
    }
    __syncthreads();
  }

  // row norms: reduce ss over the 16 l16-lanes, publish to LDS (2 halves by wn)
#pragma unroll
  for (int i = 0; i < 4; i++)
#pragma unroll
    for (int rr = 0; rr < 4; rr++) {
      float v = ss[i][rr];
      v += __shfl_xor(v, 1); v += __shfl_xor(v, 2);
      v += __shfl_xor(v, 4); v += __shfl_xor(v, 8);
      if (l16 == 0) vnLds[(wave >> 1) * 128 + wm + i * 16 + quad * 4 + rr] = v;
    }
  __syncthreads();

  // normalize + mask + write sim (and positive_map)
  const int b0 = m0 >> 10;
#pragma unroll
  for (int j2 = 0; j2 < 2; j2++) {
    const int ml = wave * 32 + j2 * 16 + l16;
    const float nv = vnLds[ml] + vnLds[128 + ml];
    const float invVn = 1.f / fmaxf(sqrtf(nv), 1e-8f);
    const int mk = mask[m0 + ml];
#pragma unroll
    for (int i2 = 0; i2 < 4; i2++) {
#pragma unroll
      for (int reg = 0; reg < 4; reg++) {
        const int s = i2 * 16 + quad * 4 + reg;
        float val = acc2[i2][j2][reg] * invVn * invSnLds[s];
        if (mk == 0) val = -__builtin_inff();
        sim[(size_t)s * MDIM + m0 + ml] = val;
        if (s == b0) pm[m0 + ml] = val;
      }
    }
  }
}

// ---------------------------------------------------------------------------
// 7) per-(s,b): top-50, IoU penalty, score — ONE WAVE per (s,b), zero barriers
// grid (1024), 256 thr (4 waves)
__global__ void k_topk(const float* __restrict__ sim, const float* __restrict__ iou,
                       const float* __restrict__ lam, float* __restrict__ scores) {
  const int wave = threadIdx.x >> 6, lane = threadIdx.x & 63;
  const int sb = blockIdx.x * 4 + wave;
  const int s = sb >> 6, b = sb & 63;
  __shared__ float tvs[4][VNUM];
  __shared__ int tis[4][VNUM];

  const float* row = sim + (size_t)s * MDIM + (size_t)b * 1024;
  float v[16];
#pragma unroll
  for (int j = 0; j < 16; j++) v[j] = row[j * 64 + lane];

  for (int k = 0; k < VNUM; k++) {
    float bv = v[0]; int bj = 0;
#pragma unroll
    for (int j = 1; j < 16; j++)
      if (v[j] > bv) { bv = v[j]; bj = j; }
    int bidx = bj * 64 + lane;
#pragma unroll
    for (int o = 1; o < 64; o <<= 1) {
      const float ov = __shfl_xor(bv, o);
      const int oi = __shfl_xor(bidx, o);
      if (ov > bv || (ov == bv && oi < bidx)) { bv = ov; bidx = oi; }
    }
    if (lane == 0) { tvs[wave][k] = bv; tis[wave][k] = bidx; }
    const int wj = bidx >> 6;
    const bool mine = (bidx & 63) == lane;
#pragma unroll
    for (int j = 0; j < 16; j++)
      if (mine && wj == j) v[j] = -__builtin_inff();
  }
  __syncthreads();

  float contrib = 0.f;
  if (lane < VNUM) {
    const int myidx = tis[wave][lane];
    float pen = 0.f;
    for (int l = lane + 1; l < VNUM; l++) {
      const float u = iou[(size_t)tis[wave][l] * 1024 + myidx];
      pen += u * u;
    }
    contrib = tvs[wave][lane] * expf(-pen / lam[0]);
  }
#pragma unroll
  for (int o = 32; o; o >>= 1) contrib += __shfl_down(contrib, o);
  if (lane == 0) scores[s * 64 + b] = contrib * (1.f / VNUM);
}

// ---------------------------------------------------------------------------
// 8) final 64x64 loss reduction
__global__ void k_loss(const float* __restrict__ scores, float* __restrict__ out) {
  __shared__ float S[64 * 64];
  __shared__ float diag[64];
  __shared__ float rmax[64], cmax[64];
  const int tid = threadIdx.x;
#pragma unroll
  for (int q = 0; q < 16; q++) S[tid + q * 256] = scores[tid + q * 256];
  __syncthreads();
  if (tid < 64) diag[tid] = S[tid * 64 + tid];
  __syncthreads();
  if (tid < 64) {
    float rm = 0.f, cm = 0.f;
    for (int x = 0; x < 64; x++) {
      if (x != tid) {
        const float cs = 0.2f + S[tid * 64 + x] - diag[tid];
        rm = fmaxf(rm, fmaxf(cs, 0.f));
        const float ci = 0.2f + S[x * 64 + tid] - diag[tid];
        cm = fmaxf(cm, fmaxf(ci, 0.f));
      }
    }
    rmax[tid] = rm; cmax[tid] = cm;
  }
  __syncthreads();
  if (tid == 0) {
    float L = 0.f;
    for (int t = 0; t < 64; t++) L += rmax[t] + cmax[t];
    out[0] = L * (1.f / 64.f);
  }
}

// ---------------------------------------------------------------------------
extern "C" void kernel_launch(void* const* d_in, const int* in_sizes, int n_in,
                              void* d_out, int out_size, void* d_ws, size_t ws_size,
                              hipStream_t stream) {
  (void)in_sizes; (void)n_in; (void)out_size; (void)ws_size;
  const float* videos = (const float*)d_in[0];
  const float* sent   = (const float*)d_in[1];
  const float* lam    = (const float*)d_in[2];
  const int*   mask   = (const int*)d_in[3];
  const float* iou    = (const float*)d_in[4];
  const float* W_v    = (const float*)d_in[6];
  const float* b_v    = (const float*)d_in[7];
  const float* W_s    = (const float*)d_in[8];
  const float* b_s    = (const float*)d_in[9];
  float* out = (float*)d_out;

  char* ws = (char*)d_ws;
  unsigned short* At   = (unsigned short*)(ws + 0);           // 128 MB
  float* sim           = (float*)(ws + 134217728);            // 16 MB
  unsigned short* Wt   = (unsigned short*)(ws + 150994944);   // 2 MB
  unsigned short* scat = (unsigned short*)(ws + 153092096);   // 128 KB
  float* vsums         = (float*)(ws + 153223168);            // 256 KB
  float* snorm2        = (float*)(ws + 153485312);            // 256 B
  float* csW           = (float*)(ws + 153485568);            // 4 KB
  float* scores        = (float*)(ws + 153489664);            // 16 KB

  // zero vsums + snorm2 (adjacent)
  hipMemsetAsync(vsums, 0, 262144 + 256, stream);

  k_transpose_videos<<<dim3(16, 16, 64), 256, 0, stream>>>(videos, At, vsums);
  k_transpose_W<<<dim3(8, 32, 4), 256, 0, stream>>>(W_v, Wt);
  k_row_sums<<<256, 256, 0, stream>>>(Wt, csW, 1024);
  k_scat<<<dim3(64, 4), 256, 0, stream>>>(sent, W_s, b_s, scat, snorm2);
  k_gemm_fused<<<dim3(512), 256, 0, stream>>>(At, Wt, vsums, csW, b_v, scat,
                                              snorm2, mask, sim, out + 1);
  k_topk<<<dim3(1024), 256, 0, stream>>>(sim, iou, lam, scores);
  k_loss<<<1, 256, 0, stream>>>(scores, out);
}